// Round 7
// baseline (196.239 us; speedup 1.0000x reference)
//
#include <hip/hip_runtime.h>
#include <math.h>

// Model collapses (softmax over a length-1 key axis == 1.0 => ctx == V) to a
// per-row MLP on biobert_cls [256,768]:
//   V      = bio @ ca_wv + ca_bv                 [256,256]
//   ctx    = LN(V @ ca_wo + ca_bo; ca_ln)
//   ffn    = relu(ctx @ w1 + b1) @ w2 + b2
//   outr   = LN(ctx + ffn; fn)
//   logits = outr @ fc_w + fc_b                  [256,5]
//
// R7 = R6 MEASUREMENT PROBE: kernel code identical to R6; main kernel is
// launched 3x (idempotent recompute, same work every call). Bench delta vs
// R6 (167.7us) = 2x warm main-kernel duration — resolves whether the kernel
// is ~31us (serialized-overhead model) or ~8us (harness-floor model), since
// rocprof top-5 is crowded out by the 41us workspace poison fills.

#define WV_ELEMS   (768 * 256)
#define W256_ELEMS (256 * 256)

__device__ __forceinline__ unsigned short f2bf_rne(float x) {
    unsigned u = __float_as_uint(x);
    unsigned r = (u + 0x7fffu + ((u >> 16) & 1u)) >> 16;   // round-nearest-even
    return (unsigned short)r;
}
__device__ __forceinline__ float bf_lo(unsigned u) { return __uint_as_float(u << 16); }
__device__ __forceinline__ float bf_hi(unsigned u) { return __uint_as_float(u & 0xffff0000u); }

// Pack wv(768x256), wo, w1, w2 (256x256 each) into bf16 at d_ws.
// 98304 float4 slots = 384 blocks x 256 threads.
__global__ __launch_bounds__(256)
void cvt_weights(const float* __restrict__ wv, const float* __restrict__ wo,
                 const float* __restrict__ w1, const float* __restrict__ w2,
                 unsigned short* __restrict__ dst) {
    int i = blockIdx.x * 256 + threadIdx.x;    // float4 slot
    const float4* src; int li;
    if (i < 49152)      { src = (const float4*)wv; li = i; }
    else if (i < 65536) { src = (const float4*)wo; li = i - 49152; }
    else if (i < 81920) { src = (const float4*)w1; li = i - 65536; }
    else                { src = (const float4*)w2; li = i - 81920; }
    float4 v = src[li];
    ushort4 o;
    o.x = f2bf_rne(v.x); o.y = f2bf_rne(v.y); o.z = f2bf_rne(v.z); o.w = f2bf_rne(v.w);
    ((ushort4*)dst)[i] = o;
}

// LN stats over the 256 values held by threads tid<256 (x must be 0 for
// tid>=256). All 1024 threads call (uniform barriers).
__device__ __forceinline__ void ln_stats(float x, int tid, float* sred,
                                         float& m, float& rs) {
    float sum = x, sq = x * x;
    #pragma unroll
    for (int o = 32; o > 0; o >>= 1) {
        sum += __shfl_down(sum, o);
        sq  += __shfl_down(sq,  o);
    }
    const int lane = tid & 63, w = tid >> 6;
    if (lane == 0 && w < 4) { sred[w] = sum; sred[4 + w] = sq; }
    __syncthreads();
    if (tid == 0) {
        float S = sred[0] + sred[1] + sred[2] + sred[3];
        float Q = sred[4] + sred[5] + sred[6] + sred[7];
        float mm  = S * (1.0f / 256.0f);
        float var = Q * (1.0f / 256.0f) - mm * mm;   // biased var (jnp.var)
        sred[0] = mm;
        sred[1] = rsqrtf(fmaxf(var, 0.0f) + 1e-5f);
    }
    __syncthreads();
    m  = sred[0];
    rs = sred[1];
    __syncthreads();                                  // protect before reuse
}

__global__ __launch_bounds__(1024)
void mlp_head_kernel(const float* __restrict__ bio,          // [256,768]
                     const unsigned short* __restrict__ wpack,
                     const float* __restrict__ bv, const float* __restrict__ bo,
                     const float* __restrict__ lng, const float* __restrict__ lnb,
                     const float* __restrict__ b1, const float* __restrict__ b2,
                     const float* __restrict__ fng, const float* __restrict__ fnb,
                     const float* __restrict__ fcw, const float* __restrict__ fcb,
                     float* __restrict__ out)                // [256,5]
{
    const int b   = blockIdx.x;     // row
    const int tid = threadIdx.x;
    const int q   = tid >> 6;       // K-group 0..15 (wave id)
    const int co  = tid & 63;       // channel quad: 4co..4co+3

    const unsigned short* wv16 = wpack;
    const unsigned short* wo16 = wpack + WV_ELEMS;
    const unsigned short* w116 = wo16 + W256_ELEMS;
    const unsigned short* w216 = w116 + W256_ELEMS;

    __shared__ float s_bio[768];
    __shared__ float s_act[256];
    __shared__ float s_part[16][256];
    __shared__ float s_red[8];

    if (tid < 768) s_bio[tid] = bio[b * 768 + tid];
    __syncthreads();

    // GEMM partial: bf16 weights [k][256]; this thread covers K rows
    // q*KG..q*KG+KG-1, channels 4co..4co+3. Trailing sync included.
    #define GEMM_BF16(W16, KG, SRC) {                                         \
        float4 a0 = {0, 0, 0, 0};                                             \
        const uint2* wp = (const uint2*)(W16) + (q * (KG)) * 64 + co;         \
        const float* x0 = (SRC) + q * (KG);                                   \
        _Pragma("unroll 16")                                                  \
        for (int k = 0; k < (KG); ++k) {                                      \
            uint2 u = wp[k * 64];                                             \
            float v0 = x0[k];                                                 \
            a0.x = fmaf(v0, bf_lo(u.x), a0.x);                                \
            a0.y = fmaf(v0, bf_hi(u.x), a0.y);                                \
            a0.z = fmaf(v0, bf_lo(u.y), a0.z);                                \
            a0.w = fmaf(v0, bf_hi(u.y), a0.w);                                \
        }                                                                     \
        ((float4*)s_part[q])[co] = a0;                                        \
    }                                                                         \
    __syncthreads();

    // Thread tid<256 owns output channel tid.
    #define REDUCE1(V) {                                                      \
        float p_ = 0.f;                                                       \
        _Pragma("unroll")                                                     \
        for (int g = 0; g < 16; ++g) p_ += s_part[g][tid];                    \
        V = p_;                                                               \
    }

    // ---- V = bio @ wv + bv ----
    GEMM_BF16(wv16, 48, s_bio);
    if (tid < 256) {
        float p; REDUCE1(p);
        s_act[tid] = p + bv[tid];
    }
    __syncthreads();

    // ---- t = V @ wo + bo ; ctx = LN(t) ----
    float ctx = 0.f;                       // live in tid<256 only
    GEMM_BF16(wo16, 16, s_act);
    {
        float t = 0.f;
        if (tid < 256) {
            float p; REDUCE1(p);
            t = p + bo[tid];
        }
        float m, rs;
        ln_stats(t, tid, s_red, m, rs);
        if (tid < 256) {
            ctx = (t - m) * rs * lng[tid] + lnb[tid];
            s_act[tid] = ctx;
        }
    }
    __syncthreads();

    // ---- u = relu(ctx @ w1 + b1) ----
    GEMM_BF16(w116, 16, s_act);
    if (tid < 256) {
        float p; REDUCE1(p);
        s_act[tid] = fmaxf(p + b1[tid], 0.0f);
    }
    __syncthreads();

    // ---- f = u @ w2 + b2 ; outr = LN(ctx + f) ----
    GEMM_BF16(w216, 16, s_act);
    {
        float o = 0.f;
        if (tid < 256) {
            float p; REDUCE1(p);
            o = p + b2[tid] + ctx;
        }
        float m, rs;
        ln_stats(o, tid, s_red, m, rs);
        if (tid < 256) s_act[tid] = (o - m) * rs * fng[tid] + fnb[tid];
    }
    __syncthreads();

    // ---- logits = outr @ fc_w + fc_b  (fc_w is [256,5]) ----
    // wave 0: lane l sums k = l + 64e over all 5 classes.
    if (q == 0) {
        float acc[5] = {0, 0, 0, 0, 0};
        #pragma unroll
        for (int e = 0; e < 4; ++e) {
            int k = co + 64 * e;
            float xv = s_act[k];
            #pragma unroll
            for (int c = 0; c < 5; ++c) acc[c] = fmaf(xv, fcw[k * 5 + c], acc[c]);
        }
        #pragma unroll
        for (int o2 = 32; o2 > 0; o2 >>= 1) {
            #pragma unroll
            for (int c = 0; c < 5; ++c) acc[c] += __shfl_down(acc[c], o2);
        }
        if (co == 0) {
            #pragma unroll
            for (int c = 0; c < 5; ++c) out[b * 5 + c] = acc[c] + fcb[c];
        }
    }
    #undef GEMM_BF16
    #undef REDUCE1
}

extern "C" void kernel_launch(void* const* d_in, const int* in_sizes, int n_in,
                              void* d_out, int out_size, void* d_ws, size_t ws_size,
                              hipStream_t stream) {
    // input order: 0:x 1:biobert_cls 2..25 gat/bn params (dead)
    // 26:ca_wq 27:ca_bq 28:ca_wk 29:ca_bk 30:ca_wv 31:ca_bv 32:ca_wo 33:ca_bo
    // 34:ca_ln_g 35:ca_ln_b 36:ffn_w1 37:ffn_b1 38:ffn_w2 39:ffn_b2
    // 40:fc_w 41:fc_b 42:fn_g 43:fn_b 44:edge_src 45:edge_dst 46:batch
    const float* bio = (const float*)d_in[1];
    const float* wv  = (const float*)d_in[30];
    const float* bv  = (const float*)d_in[31];
    const float* wo  = (const float*)d_in[32];
    const float* bo  = (const float*)d_in[33];
    const float* lng = (const float*)d_in[34];
    const float* lnb = (const float*)d_in[35];
    const float* w1  = (const float*)d_in[36];
    const float* b1  = (const float*)d_in[37];
    const float* w2  = (const float*)d_in[38];
    const float* b2  = (const float*)d_in[39];
    const float* fcw = (const float*)d_in[40];
    const float* fcb = (const float*)d_in[41];
    const float* fng = (const float*)d_in[42];
    const float* fnb = (const float*)d_in[43];
    float* out = (float*)d_out;
    unsigned short* wpack = (unsigned short*)d_ws;   // 786432 bf16 = 1.5 MB

    hipLaunchKernelGGL(cvt_weights, dim3(384), dim3(256), 0, stream,
                       wv, wo, w1, w2, wpack);
    // PROBE: 3 idempotent launches. #2/#3 recompute identical d_out from
    // unchanged inputs (same work every call; graph-capture safe).
    // Bench delta vs R6 / 2 = warm per-launch duration of this kernel.
    for (int rep = 0; rep < 3; ++rep) {
        hipLaunchKernelGGL(mlp_head_kernel, dim3(256), dim3(1024), 0, stream,
                           bio, wpack, bv, bo, lng, lnb, b1, b2,
                           fng, fnb, fcw, fcb, out);
    }
}

// Round 8
// 158.540 us; speedup vs baseline: 1.2378x; 1.2378x over previous
//
#include <hip/hip_runtime.h>
#include <math.h>

// Model collapses (softmax over a length-1 key axis == 1.0 => ctx == V) to a
// per-row MLP on biobert_cls [256,768]:
//   V      = bio @ ca_wv + ca_bv                 [256,256]
//   ctx    = LN(V @ ca_wo + ca_bo; ca_ln)
//   ffn    = relu(ctx @ w1 + b1) @ w2 + b2
//   outr   = LN(ctx + ffn; fn)
//   logits = outr @ fc_w + fc_b                  [256,5]
//
// R8: probe (R7) measured main kernel = 14.3us warm. Attack the serial
// latency exposure: (a) LDS-only barriers (s_waitcnt lgkmcnt(0); s_barrier)
// leave global loads in flight across barriers; (b) next-stage weights
// register-prefetched before each barrier; (c) weights repacked so each load
// is a 16B dwordx4 (k-pair x 4 channels); (d) biases/LN params/fc_w
// front-loaded. Numerics bit-identical to R6 (absmax must be 0.015625).

#define WV_U4   24576      // wv  : 384 kp-rows x 64 uint4
#define W256_U4 8192       // wo/w1/w2 : 128 kp-rows x 64 uint4

__device__ __forceinline__ unsigned short f2bf_rne(float x) {
    unsigned u = __float_as_uint(x);
    unsigned r = (u + 0x7fffu + ((u >> 16) & 1u)) >> 16;   // round-nearest-even
    return (unsigned short)r;
}
__device__ __forceinline__ float bf_lo(unsigned u) { return __uint_as_float(u << 16); }
__device__ __forceinline__ float bf_hi(unsigned u) { return __uint_as_float(u & 0xffff0000u); }
__device__ __forceinline__ unsigned packbf(float e, float o) {
    return (unsigned)f2bf_rne(e) | ((unsigned)f2bf_rne(o) << 16);
}

// LDS-only barrier: drains LDS ops, leaves global register loads in flight.
// Safe here: all cross-thread communication goes through LDS (lgkm-counted);
// global loads feed only private registers.
__device__ __forceinline__ void lds_barrier() {
    asm volatile("s_waitcnt lgkmcnt(0)\n\ts_barrier" ::: "memory");
}

// Pack k-pairs: dst[m][kp][c] = (bf(w[2kp+1][c])<<16) | bf(w[2kp][c]).
// 49152 uint4 slots = 192 blocks x 256 threads.
__global__ __launch_bounds__(256)
void cvt_weights(const float* __restrict__ wv, const float* __restrict__ wo,
                 const float* __restrict__ w1, const float* __restrict__ w2,
                 uint4* __restrict__ dst) {
    int i = blockIdx.x * 256 + threadIdx.x;    // uint4 slot
    const float4* src; int li;
    if (i < 24576)      { src = (const float4*)wv; li = i; }
    else if (i < 32768) { src = (const float4*)wo; li = i - 24576; }
    else if (i < 40960) { src = (const float4*)w1; li = i - 32768; }
    else                { src = (const float4*)w2; li = i - 40960; }
    int kp = li >> 6, c4 = li & 63;
    float4 r0 = src[(2 * kp) * 64 + c4];       // even k  -> low 16
    float4 r1 = src[(2 * kp + 1) * 64 + c4];   // odd  k  -> high 16
    uint4 o;
    o.x = packbf(r0.x, r1.x);
    o.y = packbf(r0.y, r1.y);
    o.z = packbf(r0.z, r1.z);
    o.w = packbf(r0.w, r1.w);
    dst[i] = o;
}

// LN stats over 256 values held by tid<256 (x==0 for tid>=256); sred = 8-float
// region, caller alternates regions. All 1024 threads call.
__device__ __forceinline__ void ln_stats(float x, int tid, float* sred,
                                         float& m, float& rs) {
    float sum = x, sq = x * x;
    #pragma unroll
    for (int o = 32; o > 0; o >>= 1) {
        sum += __shfl_down(sum, o);
        sq  += __shfl_down(sq,  o);
    }
    const int lane = tid & 63, w = tid >> 6;
    if (lane == 0 && w < 4) { sred[w] = sum; sred[4 + w] = sq; }
    lds_barrier();
    if (tid == 0) {
        float S = sred[0] + sred[1] + sred[2] + sred[3];
        float Q = sred[4] + sred[5] + sred[6] + sred[7];
        float mm  = S * (1.0f / 256.0f);
        float var = Q * (1.0f / 256.0f) - mm * mm;   // biased var (jnp.var)
        sred[0] = mm;
        sred[1] = rsqrtf(fmaxf(var, 0.0f) + 1e-5f);
    }
    lds_barrier();
    m  = sred[0];
    rs = sred[1];
}

__global__ __launch_bounds__(1024)
void mlp_head_kernel(const float* __restrict__ bio,          // [256,768]
                     const uint4* __restrict__ wpack,
                     const float* __restrict__ bv, const float* __restrict__ bo,
                     const float* __restrict__ lng, const float* __restrict__ lnb,
                     const float* __restrict__ b1, const float* __restrict__ b2,
                     const float* __restrict__ fng, const float* __restrict__ fnb,
                     const float* __restrict__ fcw, const float* __restrict__ fcb,
                     float* __restrict__ out)                // [256,5]
{
    const int b   = blockIdx.x;     // row
    const int tid = threadIdx.x;
    const int q   = tid >> 6;       // K-group 0..15 (wave id)
    const int co  = tid & 63;       // channel quad: 4co..4co+3
    const int cc  = tid & 255;

    const uint4* wv4 = wpack;
    const uint4* wo4 = wpack + WV_U4;
    const uint4* w14 = wo4 + W256_U4;
    const uint4* w24 = w14 + W256_U4;

    __shared__ __align__(16) float s_bio[768];
    __shared__ __align__(16) float s_act[256];
    __shared__ __align__(16) float s_part[16][256];
    __shared__ float s_red[16];
    __shared__ float s_fcw[1280];

    // ---- front-loaded independent loads (all issue before any wait) ----
    uint4 w_pre[8];                               // stage-2 (wo) weights
    {
        const uint4* pp = wo4 + (q * 8) * 64 + co;
        #pragma unroll
        for (int t = 0; t < 8; ++t) w_pre[t] = pp[t * 64];
        #pragma unroll
        for (int t = 0; t < 8; ++t) asm volatile("" : "+v"(w_pre[t].x));
    }
    float bvv = bv[cc], bov = bo[cc], lngv = lng[cc], lnbv = lnb[cc];
    float b1v = b1[cc], b2v = b2[cc], fngv = fng[cc], fnbv = fnb[cc];
    float fb[5];
    #pragma unroll
    for (int c = 0; c < 5; ++c) fb[c] = fcb[c];   // uniform -> scalar loads

    if (tid < 768) {
        s_bio[tid] = bio[b * 768 + tid];
    } else {
        int t0 = tid - 768;                       // 256 threads x 5 = fc_w
        #pragma unroll
        for (int e = 0; e < 5; ++e) s_fcw[t0 + 256 * e] = fcw[t0 + 256 * e];
    }
    lds_barrier();

    // ---- stage 1: V = bio @ wv + bv  (24 uint4 per thread) ----
    {
        float4 a = {0, 0, 0, 0};
        const uint4* wp = wv4 + (q * 24) * 64 + co;
        const float* x0 = s_bio + q * 48;
        #pragma unroll 8
        for (int kp = 0; kp < 24; ++kp) {
            uint4 u = wp[kp * 64];
            float xe = x0[2 * kp], xo = x0[2 * kp + 1];
            a.x = fmaf(xe, bf_lo(u.x), a.x); a.x = fmaf(xo, bf_hi(u.x), a.x);
            a.y = fmaf(xe, bf_lo(u.y), a.y); a.y = fmaf(xo, bf_hi(u.y), a.y);
            a.z = fmaf(xe, bf_lo(u.z), a.z); a.z = fmaf(xo, bf_hi(u.z), a.z);
            a.w = fmaf(xe, bf_lo(u.w), a.w); a.w = fmaf(xo, bf_hi(u.w), a.w);
        }
        ((float4*)s_part[q])[co] = a;
    }
    lds_barrier();
    if (tid < 256) {
        float p = 0.f;
        #pragma unroll
        for (int g = 0; g < 16; ++g) p += s_part[g][tid];
        s_act[tid] = p + bvv;
    }
    lds_barrier();

    // consume w_pre (8 uint4) against s_act slice, then write s_part
    #define GEMM_REG() {                                                      \
        float4 a = {0, 0, 0, 0};                                              \
        const float* x0 = s_act + q * 16;                                     \
        _Pragma("unroll")                                                     \
        for (int t = 0; t < 8; ++t) {                                         \
            uint4 u = w_pre[t];                                               \
            float xe = x0[2 * t], xo = x0[2 * t + 1];                         \
            a.x = fmaf(xe, bf_lo(u.x), a.x); a.x = fmaf(xo, bf_hi(u.x), a.x); \
            a.y = fmaf(xe, bf_lo(u.y), a.y); a.y = fmaf(xo, bf_hi(u.y), a.y); \
            a.z = fmaf(xe, bf_lo(u.z), a.z); a.z = fmaf(xo, bf_hi(u.z), a.z); \
            a.w = fmaf(xe, bf_lo(u.w), a.w); a.w = fmaf(xo, bf_hi(u.w), a.w); \
        }                                                                     \
        ((float4*)s_part[q])[co] = a;                                         \
    }
    #define PREFETCH(BASE) {                                                  \
        const uint4* pp = (BASE) + (q * 8) * 64 + co;                         \
        _Pragma("unroll")                                                     \
        for (int t = 0; t < 8; ++t) w_pre[t] = pp[t * 64];                    \
        _Pragma("unroll")                                                     \
        for (int t = 0; t < 8; ++t) asm volatile("" : "+v"(w_pre[t].x));      \
    }
    #define REDUCE1(V) {                                                      \
        float p_ = 0.f;                                                       \
        _Pragma("unroll")                                                     \
        for (int g = 0; g < 16; ++g) p_ += s_part[g][tid];                    \
        V = p_;                                                               \
    }

    // ---- stage 2: t = V @ wo + bo ; ctx = LN(t) ----
    GEMM_REG();
    PREFETCH(w14);                   // stage-3 weights fly across barrier+LN
    lds_barrier();
    float ctx = 0.f;
    {
        float t = 0.f;
        if (tid < 256) {
            float p; REDUCE1(p);
            t = p + bov;
        }
        float m, rs;
        ln_stats(t, tid, s_red, m, rs);        // region 0
        if (tid < 256) {
            ctx = (t - m) * rs * lngv + lnbv;
            s_act[tid] = ctx;
        }
    }
    lds_barrier();

    // ---- stage 3: u = relu(ctx @ w1 + b1) ----
    GEMM_REG();
    PREFETCH(w24);                   // stage-4 weights
    lds_barrier();
    if (tid < 256) {
        float p; REDUCE1(p);
        s_act[tid] = fmaxf(p + b1v, 0.0f);
    }
    lds_barrier();

    // ---- stage 4: f = u @ w2 + b2 ; outr = LN(ctx + f) ----
    GEMM_REG();
    lds_barrier();
    {
        float o = 0.f;
        if (tid < 256) {
            float p; REDUCE1(p);
            o = p + b2v + ctx;
        }
        float m, rs;
        ln_stats(o, tid, s_red + 8, m, rs);    // region 1
        if (tid < 256) s_act[tid] = (o - m) * rs * fngv + fnbv;
    }
    lds_barrier();

    // ---- logits = outr @ fc_w + fc_b  (fc_w staged in LDS) ----
    if (q == 0) {
        float acc[5] = {0, 0, 0, 0, 0};
        #pragma unroll
        for (int e = 0; e < 4; ++e) {
            int k = co + 64 * e;
            float xv = s_act[k];
            #pragma unroll
            for (int c = 0; c < 5; ++c) acc[c] = fmaf(xv, s_fcw[k * 5 + c], acc[c]);
        }
        #pragma unroll
        for (int o2 = 32; o2 > 0; o2 >>= 1) {
            #pragma unroll
            for (int c = 0; c < 5; ++c) acc[c] += __shfl_down(acc[c], o2);
        }
        if (co == 0) {
            #pragma unroll
            for (int c = 0; c < 5; ++c) out[b * 5 + c] = acc[c] + fb[c];
        }
    }
    #undef GEMM_REG
    #undef PREFETCH
    #undef REDUCE1
}

extern "C" void kernel_launch(void* const* d_in, const int* in_sizes, int n_in,
                              void* d_out, int out_size, void* d_ws, size_t ws_size,
                              hipStream_t stream) {
    // input order: 0:x 1:biobert_cls 2..25 gat/bn params (dead)
    // 26:ca_wq 27:ca_bq 28:ca_wk 29:ca_bk 30:ca_wv 31:ca_bv 32:ca_wo 33:ca_bo
    // 34:ca_ln_g 35:ca_ln_b 36:ffn_w1 37:ffn_b1 38:ffn_w2 39:ffn_b2
    // 40:fc_w 41:fc_b 42:fn_g 43:fn_b 44:edge_src 45:edge_dst 46:batch
    const float* bio = (const float*)d_in[1];
    const float* wv  = (const float*)d_in[30];
    const float* bv  = (const float*)d_in[31];
    const float* wo  = (const float*)d_in[32];
    const float* bo  = (const float*)d_in[33];
    const float* lng = (const float*)d_in[34];
    const float* lnb = (const float*)d_in[35];
    const float* w1  = (const float*)d_in[36];
    const float* b1  = (const float*)d_in[37];
    const float* w2  = (const float*)d_in[38];
    const float* b2  = (const float*)d_in[39];
    const float* fcw = (const float*)d_in[40];
    const float* fcb = (const float*)d_in[41];
    const float* fng = (const float*)d_in[42];
    const float* fnb = (const float*)d_in[43];
    float* out = (float*)d_out;
    uint4* wpack = (uint4*)d_ws;                 // 49152 uint4 = 768 KB

    hipLaunchKernelGGL(cvt_weights, dim3(192), dim3(256), 0, stream,
                       wv, wo, w1, w2, wpack);
    hipLaunchKernelGGL(mlp_head_kernel, dim3(256), dim3(1024), 0, stream,
                       bio, wpack, bv, bo, lng, lnb, b1, b2,
                       fng, fnb, fcw, fcb, out);
}